// Round 4
// baseline (577.857 us; speedup 1.0000x reference)
//
#include <hip/hip_runtime.h>

#define D 128
#define NN 100000
#define NE 1600000
#define SCAN_NBLK 98        // ceil(NN / 1024)
#define GT_ROWS 128
#define GEMM_NT ((NN + GT_ROWS - 1) / GT_ROWS)   // 782
#define GEMM_GRID 512
#define NRANGE 8
#define RANGE_SZ 12500
#define STREAM_CAP 204800   // 200000 avg + 11 sigma slack
#define BINA_GRID 256
#define FILLB_GRID 1024

// ---------------------------------------------------------------------------
// K0: init the 8 stream cursors
// ---------------------------------------------------------------------------
__global__ void init8_kernel(unsigned int* __restrict__ gcur8)
{
    if (threadIdx.x < NRANGE) gcur8[threadIdx.x] = threadIdx.x * STREAM_CAP;
}

// ---------------------------------------------------------------------------
// K1: fused degree-count + XCD-range binning.
// pass1: cnt[dst]++ (global) and cnt8[dst/12500]++ (LDS)
// pass2: write packed (dstLocal<<17 | src) into per-range stream, block-coalesced
// ---------------------------------------------------------------------------
__global__ __launch_bounds__(256) void bin_count_kernel(
    const int* __restrict__ src, const int* __restrict__ dst,
    int* __restrict__ cnt, unsigned int* __restrict__ gcur8,
    unsigned int* __restrict__ stream)
{
    __shared__ unsigned int cnt8[NRANGE], base8[NRANGE], off8[NRANGE];
    const int tid = threadIdx.x;
    if (tid < NRANGE) cnt8[tid] = 0;
    __syncthreads();
    const int NT4 = NE / 4;
    // pass 1
    for (int i4 = blockIdx.x * 256 + tid; i4 < NT4; i4 += BINA_GRID * 256) {
        int4 d = ((const int4*)dst)[i4];
        atomicAdd(&cnt[d.x], 1);
        atomicAdd(&cnt[d.y], 1);
        atomicAdd(&cnt[d.z], 1);
        atomicAdd(&cnt[d.w], 1);
        atomicAdd(&cnt8[d.x / RANGE_SZ], 1u);
        atomicAdd(&cnt8[d.y / RANGE_SZ], 1u);
        atomicAdd(&cnt8[d.z / RANGE_SZ], 1u);
        atomicAdd(&cnt8[d.w / RANGE_SZ], 1u);
    }
    __syncthreads();
    if (tid < NRANGE) {
        base8[tid] = atomicAdd(&gcur8[tid], cnt8[tid]);
        off8[tid]  = 0;
    }
    __syncthreads();
    // pass 2
    for (int i4 = blockIdx.x * 256 + tid; i4 < NT4; i4 += BINA_GRID * 256) {
        int4 d = ((const int4*)dst)[i4];
        int4 s = ((const int4*)src)[i4];
        {
            int r = d.x / RANGE_SZ; unsigned dl = (unsigned)(d.x - r * RANGE_SZ);
            unsigned pos = base8[r] + atomicAdd(&off8[r], 1u);
            stream[pos] = (dl << 17) | (unsigned)s.x;
        }
        {
            int r = d.y / RANGE_SZ; unsigned dl = (unsigned)(d.y - r * RANGE_SZ);
            unsigned pos = base8[r] + atomicAdd(&off8[r], 1u);
            stream[pos] = (dl << 17) | (unsigned)s.y;
        }
        {
            int r = d.z / RANGE_SZ; unsigned dl = (unsigned)(d.z - r * RANGE_SZ);
            unsigned pos = base8[r] + atomicAdd(&off8[r], 1u);
            stream[pos] = (dl << 17) | (unsigned)s.z;
        }
        {
            int r = d.w / RANGE_SZ; unsigned dl = (unsigned)(d.w - r * RANGE_SZ);
            unsigned pos = base8[r] + atomicAdd(&off8[r], 1u);
            stream[pos] = (dl << 17) | (unsigned)s.w;
        }
    }
}

// ---------------------------------------------------------------------------
// K2: per-block exclusive scan (1024 elements / block)
// ---------------------------------------------------------------------------
__global__ __launch_bounds__(256) void scan_local_kernel(
    const int* __restrict__ cnt, int* __restrict__ pre, int* __restrict__ blkSum)
{
    __shared__ int lds[256];
    const int t = threadIdx.x;
    const int base = blockIdx.x * 1024 + t * 4;
    int4 v = {0, 0, 0, 0};
    if (base + 3 < NN) v = *(const int4*)&cnt[base];
    else {
        if (base + 0 < NN) v.x = cnt[base + 0];
        if (base + 1 < NN) v.y = cnt[base + 1];
        if (base + 2 < NN) v.z = cnt[base + 2];
        if (base + 3 < NN) v.w = cnt[base + 3];
    }
    const int s = v.x + v.y + v.z + v.w;
    lds[t] = s;
    __syncthreads();
    for (int off = 1; off < 256; off <<= 1) {
        int val = 0;
        if (t >= off) val = lds[t - off];
        __syncthreads();
        if (t >= off) lds[t] += val;
        __syncthreads();
    }
    const int excl = lds[t] - s;
    if (t == 255) blkSum[blockIdx.x] = lds[255];
    int4 o;
    o.x = excl;
    o.y = excl + v.x;
    o.z = excl + v.x + v.y;
    o.w = excl + v.x + v.y + v.z;
    if (base + 3 < NN) *(int4*)&pre[base] = o;
    else {
        if (base + 0 < NN) pre[base + 0] = o.x;
        if (base + 1 < NN) pre[base + 1] = o.y;
        if (base + 2 < NN) pre[base + 2] = o.z;
        if (base + 3 < NN) pre[base + 3] = o.w;
    }
}

// ---------------------------------------------------------------------------
// K3: scan the 98 block sums (single block)
// ---------------------------------------------------------------------------
__global__ __launch_bounds__(128) void scan_blk_kernel(
    const int* __restrict__ blkSum, int* __restrict__ blkOfs)
{
    __shared__ int lds[128];
    const int t = threadIdx.x;
    int s = (t < SCAN_NBLK) ? blkSum[t] : 0;
    lds[t] = s;
    __syncthreads();
    for (int off = 1; off < 128; off <<= 1) {
        int val = 0;
        if (t >= off) val = lds[t - off];
        __syncthreads();
        if (t >= off) lds[t] += val;
        __syncthreads();
    }
    blkOfs[t] = lds[t] - s;
}

// ---------------------------------------------------------------------------
// K4: row_start[n] = pre[n] + blkOfs[n/1024]; cursor = copy
// ---------------------------------------------------------------------------
__global__ __launch_bounds__(256) void scan_finish_kernel(
    const int* __restrict__ pre, const int* __restrict__ blkOfs,
    int* __restrict__ row_start, int* __restrict__ cursor)
{
    int n = blockIdx.x * 256 + threadIdx.x;
    if (n > NN) return;
    int v = (n == NN) ? NE : pre[n] + blkOfs[n >> 10];
    row_start[n] = v;
    if (n < NN) cursor[n] = v;
}

// ---------------------------------------------------------------------------
// K5: fill eidx from the 8 streams; block b handles stream b&7 so each
// dst-range's cursor/eidx lines are owned by one XCD (blockIdx%8 round-robin)
// ---------------------------------------------------------------------------
__global__ __launch_bounds__(256) void fill_kernel(
    const unsigned int* __restrict__ stream, const unsigned int* __restrict__ gcur8,
    int* __restrict__ cursor, int* __restrict__ eidx)
{
    const int r = blockIdx.x & 7;
    const int chunk = blockIdx.x >> 3;               // 0..127
    const unsigned s1 = gcur8[r];                    // stream end
    const unsigned stride = (FILLB_GRID / 8) * 256;  // 32768
    for (unsigned i = (unsigned)r * STREAM_CAP + chunk * 256 + threadIdx.x;
         i < s1; i += stride) {
        unsigned p = stream[i];
        int s  = (int)(p & 0x1FFFFu);
        int dn = r * RANGE_SZ + (int)(p >> 17);
        int pos = atomicAdd(&cursor[dn], 1);
        eidx[pos] = s;
    }
}

// ---------------------------------------------------------------------------
// K6: gather  x[n] = (1+eps)*h[n] + sum_{e in csr(n)} h[eidx[e]]
// ---------------------------------------------------------------------------
__global__ __launch_bounds__(256) void gather_kernel(
    const float* __restrict__ h, const int* __restrict__ row_start,
    const int* __restrict__ eidx, const float* __restrict__ epsp,
    float* __restrict__ x)
{
    int gid  = blockIdx.x * 256 + threadIdx.x;
    int node = gid >> 5;
    int lane = gid & 31;
    if (node >= NN) return;
    const int s0 = row_start[node];
    const int s1 = row_start[node + 1];
    const float sc = 1.0f + epsp[0];
    float4 hv = ((const float4*)(h + (size_t)node * D))[lane];
    float ax = sc * hv.x, ay = sc * hv.y, az = sc * hv.z, aw = sc * hv.w;
    float bx = 0.f, by = 0.f, bz = 0.f, bw = 0.f;
    int e = s0;
    for (; e + 1 < s1; e += 2) {
        int sa = eidx[e];
        int sb = eidx[e + 1];
        float4 va = ((const float4*)(h + (size_t)sa * D))[lane];
        float4 vb = ((const float4*)(h + (size_t)sb * D))[lane];
        ax += va.x; ay += va.y; az += va.z; aw += va.w;
        bx += vb.x; by += vb.y; bz += vb.z; bw += vb.w;
    }
    if (e < s1) {
        int sa = eidx[e];
        float4 va = ((const float4*)(h + (size_t)sa * D))[lane];
        ax += va.x; ay += va.y; az += va.z; aw += va.w;
    }
    float4 o = {ax + bx, ay + by, az + bz, aw + bw};
    ((float4*)(x + (size_t)node * D))[lane] = o;
}

// ---------------------------------------------------------------------------
// K7/K8: GEMM. x-tile (64KB, swizzled, [k][row]) in LDS; W read from global
// (L2-broadcast). 256 thr, 2 blocks/CU (2 waves/SIMD), barrier-free k-loop.
// MODE 1: out = relu(x@W + b)
// MODE 2: out = (x@W + b) * snorm, fused per-column sum/sumsq -> stats
// ---------------------------------------------------------------------------
template <int MODE>
__global__ __launch_bounds__(256, 2) void gemm_kernel(
    const float* __restrict__ xin, const float* __restrict__ W,
    const float* __restrict__ bias, const float* __restrict__ snorm,
    float* __restrict__ out, double* __restrict__ stats)
{
    __shared__ float xb[D * GT_ROWS];    // 64 KB  [k][row], swizzled chunks
    const int tid = threadIdx.x;
    const int cg = tid & 15;             // col group (8 cols: ca*4, cb*4)
    const int rg = tid >> 4;             // row group (8 rows)
    const int ca = cg * 4;
    const int cb = 64 + cg * 4;
    const float4* Wv = (const float4*)W;

    float4 bva = ((const float4*)bias)[cg];
    float4 bvb = ((const float4*)bias)[16 + cg];

    float ssum[8], ssq[8];
#pragma unroll
    for (int j = 0; j < 8; ++j) { ssum[j] = 0.f; ssq[j] = 0.f; }

    float4 rstg[16];
    auto LOADT = [&](int t) {
        const int row0 = t * GT_ROWS;
#pragma unroll
        for (int i = 0; i < 16; ++i) {
            int idx = tid + i * 256;          // 0..4095
            int row = idx >> 5;               // 0..127
            int kc  = idx & 31;               // float4 k-chunk
            int grow = row0 + row;
            rstg[i] = (grow < NN)
                ? ((const float4*)(xin + (size_t)grow * D))[kc]
                : make_float4(0.f, 0.f, 0.f, 0.f);
        }
    };
    auto WRITET = [&]() {
#pragma unroll
        for (int i = 0; i < 16; ++i) {
            int idx = tid + i * 256;
            int row = idx >> 5;
            int kc  = idx & 31;
            int c4  = (row >> 2) ^ (kc & 7);          // XOR chunk swizzle
            float v[4] = {rstg[i].x, rstg[i].y, rstg[i].z, rstg[i].w};
#pragma unroll
            for (int j = 0; j < 4; ++j)
                xb[(kc * 4 + j) * GT_ROWS + c4 * 4 + (row & 3)] = v[j];
        }
    };

    bool first = true;
    for (int t = blockIdx.x; t < GEMM_NT; t += GEMM_GRID) {
        if (first) { LOADT(t); first = false; }
        __syncthreads();            // xb free (prev tile's k-loop done)
        WRITET();
        __syncthreads();            // xb visible

        float acc[8][8];
#pragma unroll
        for (int i = 0; i < 8; ++i)
#pragma unroll
            for (int j = 0; j < 8; ++j) acc[i][j] = 0.f;

#pragma unroll 4
        for (int k = 0; k < D; ++k) {
            const int sk = (k >> 2) & 7;
            float4 xa = *(const float4*)&xb[k * GT_ROWS + (((rg * 2) ^ sk) << 2)];
            float4 xc = *(const float4*)&xb[k * GT_ROWS + (((rg * 2 + 1) ^ sk) << 2)];
            float4 wa = Wv[k * 32 + cg];
            float4 wb = Wv[k * 32 + 16 + cg];
            float xr[8] = {xa.x, xa.y, xa.z, xa.w, xc.x, xc.y, xc.z, xc.w};
            float wr[8] = {wa.x, wa.y, wa.z, wa.w, wb.x, wb.y, wb.z, wb.w};
#pragma unroll
            for (int i = 0; i < 8; ++i)
#pragma unroll
                for (int j = 0; j < 8; ++j)
                    acc[i][j] = fmaf(xr[i], wr[j], acc[i][j]);
        }

        // prefetch next tile's x while epilogue stores drain
        int tn = t + GEMM_GRID;
        if (tn < GEMM_NT) LOADT(tn);

        // ---- epilogue ----
#pragma unroll
        for (int i = 0; i < 8; ++i) {
            int row = t * GT_ROWS + rg * 8 + i;
            if (row < NN) {
                float oa[4], ob[4];
                if (MODE == 1) {
                    oa[0] = fmaxf(acc[i][0] + bva.x, 0.f);
                    oa[1] = fmaxf(acc[i][1] + bva.y, 0.f);
                    oa[2] = fmaxf(acc[i][2] + bva.z, 0.f);
                    oa[3] = fmaxf(acc[i][3] + bva.w, 0.f);
                    ob[0] = fmaxf(acc[i][4] + bvb.x, 0.f);
                    ob[1] = fmaxf(acc[i][5] + bvb.y, 0.f);
                    ob[2] = fmaxf(acc[i][6] + bvb.z, 0.f);
                    ob[3] = fmaxf(acc[i][7] + bvb.w, 0.f);
                } else {
                    const float sn = snorm[row];
                    oa[0] = (acc[i][0] + bva.x) * sn;
                    oa[1] = (acc[i][1] + bva.y) * sn;
                    oa[2] = (acc[i][2] + bva.z) * sn;
                    oa[3] = (acc[i][3] + bva.w) * sn;
                    ob[0] = (acc[i][4] + bvb.x) * sn;
                    ob[1] = (acc[i][5] + bvb.y) * sn;
                    ob[2] = (acc[i][6] + bvb.z) * sn;
                    ob[3] = (acc[i][7] + bvb.w) * sn;
#pragma unroll
                    for (int j = 0; j < 4; ++j) {
                        ssum[j]     += oa[j];  ssq[j]     += oa[j] * oa[j];
                        ssum[4 + j] += ob[j];  ssq[4 + j] += ob[j] * ob[j];
                    }
                }
                float* op = out + (size_t)row * D;
                *(float4*)&op[ca] = *(float4*)&oa[0];
                *(float4*)&op[cb] = *(float4*)&ob[0];
            }
        }
    }

    // ---- fused BN stats reduce (MODE 2): reuse xb as scratch ----
    if (MODE == 2) {
        float* red = xb;
        __syncthreads();
#pragma unroll
        for (int j = 0; j < 4; ++j) {
            red[rg * D + ca + j] = ssum[j];
            red[rg * D + cb + j] = ssum[4 + j];
        }
        __syncthreads();
        if (tid < D) {
            float s = 0.f;
#pragma unroll
            for (int r = 0; r < 16; ++r) s += red[r * D + tid];
            atomicAdd(&stats[tid], (double)s);
        }
        __syncthreads();
#pragma unroll
        for (int j = 0; j < 4; ++j) {
            red[rg * D + ca + j] = ssq[j];
            red[rg * D + cb + j] = ssq[4 + j];
        }
        __syncthreads();
        if (tid < D) {
            float s = 0.f;
#pragma unroll
            for (int r = 0; r < 16; ++r) s += red[r * D + tid];
            atomicAdd(&stats[D + tid], (double)s);
        }
    }
}

// ---------------------------------------------------------------------------
// K9: fold stats into per-column scale/shift
// ---------------------------------------------------------------------------
__global__ void bn_prep_kernel(const double* __restrict__ stats,
                               const float* __restrict__ gamma,
                               const float* __restrict__ beta,
                               float* __restrict__ sc_sh)
{
    int c = threadIdx.x;
    double mean = stats[c] * (1.0 / NN);
    double var  = stats[D + c] * (1.0 / NN) - mean * mean;
    float rs = rsqrtf((float)var + 1e-5f);
    float sc = gamma[c] * rs;
    sc_sh[c]     = sc;
    sc_sh[D + c] = beta[c] - (float)mean * sc;
}

// ---------------------------------------------------------------------------
// K10: out = h + relu(y*sc + sh)
// ---------------------------------------------------------------------------
__global__ __launch_bounds__(256) void finalize_kernel(
    const float* __restrict__ y, const float* __restrict__ h,
    const float* __restrict__ sc_sh, float* __restrict__ out)
{
    int i  = blockIdx.x * 256 + threadIdx.x;
    int cf = i & 31;
    float4 yv = ((const float4*)y)[i];
    float4 hv = ((const float4*)h)[i];
    float4 sc = ((const float4*)sc_sh)[cf];
    float4 sh = ((const float4*)(sc_sh + D))[cf];
    float4 o;
    o.x = hv.x + fmaxf(fmaf(yv.x, sc.x, sh.x), 0.0f);
    o.y = hv.y + fmaxf(fmaf(yv.y, sc.y, sh.y), 0.0f);
    o.z = hv.z + fmaxf(fmaf(yv.z, sc.z, sh.z), 0.0f);
    o.w = hv.w + fmaxf(fmaf(yv.w, sc.w, sh.w), 0.0f);
    ((float4*)out)[i] = o;
}

// ---------------------------------------------------------------------------
extern "C" void kernel_launch(void* const* d_in, const int* in_sizes, int n_in,
                              void* d_out, int out_size, void* d_ws, size_t ws_size,
                              hipStream_t stream)
{
    const float* h     = (const float*)d_in[0];
    const float* snorm = (const float*)d_in[1];
    const float* eps   = (const float*)d_in[2];
    const float* W1    = (const float*)d_in[3];
    const float* b1    = (const float*)d_in[4];
    const float* W2    = (const float*)d_in[5];
    const float* b2    = (const float*)d_in[6];
    const float* gamma = (const float*)d_in[7];
    const float* beta  = (const float*)d_in[8];
    const int*   src   = (const int*)d_in[9];
    const int*   dst   = (const int*)d_in[10];
    float* out = (float*)d_out;

    char* ws = (char*)d_ws;
    const size_t BUF_BYTES = (size_t)NN * D * sizeof(float);   // 51.2 MB
    float*  buf       = (float*)ws;                            // x -> hidden -> y
    double* stats     = (double*)(ws + BUF_BYTES);             // 256 doubles
    float*  sc_sh     = (float*)(ws + BUF_BYTES + 2048);       // 256 floats
    char*   p         = ws + BUF_BYTES + 4096;
    int*    cnt       = (int*)p;            p += (size_t)NN * 4;
    int*    pre       = (int*)p;            p += (size_t)NN * 4;
    int*    row_start = (int*)p;            p += (size_t)(NN + 4) * 4;
    int*    cursor    = (int*)p;            p += (size_t)NN * 4;
    int*    blkSum    = (int*)p;            p += 512;
    int*    blkOfs    = (int*)p;            p += 512;
    unsigned int* gcur8  = (unsigned int*)p;  p += 256;
    int*    eidx      = (int*)p;            p += (size_t)NE * 4;          // 6.4 MB
    unsigned int* stream8 = (unsigned int*)p;                             // 6.55 MB

    hipMemsetAsync(cnt, 0, (size_t)NN * 4, stream);
    hipMemsetAsync(stats, 0, 2048, stream);
    init8_kernel<<<1, 64, 0, stream>>>(gcur8);

    // ---- CSR build: fused count+bin, scan, XCD-local fill ----
    bin_count_kernel<<<BINA_GRID, 256, 0, stream>>>(src, dst, cnt, gcur8, stream8);
    scan_local_kernel<<<SCAN_NBLK, 256, 0, stream>>>(cnt, pre, blkSum);
    scan_blk_kernel<<<1, 128, 0, stream>>>(blkSum, blkOfs);
    scan_finish_kernel<<<(NN + 256) / 256 + 1, 256, 0, stream>>>(pre, blkOfs, row_start, cursor);
    fill_kernel<<<FILLB_GRID, 256, 0, stream>>>(stream8, gcur8, cursor, eidx);

    // ---- gather: x = (1+eps)*h + segment_sum(h[src] by dst) ----
    gather_kernel<<<NN * 32 / 256, 256, 0, stream>>>(h, row_start, eidx, eps, buf);

    // ---- MLP (in-place on buf), BN stats fused into GEMM2 ----
    gemm_kernel<1><<<GEMM_GRID, 256, 0, stream>>>(buf, W1, b1, nullptr, buf, nullptr);
    gemm_kernel<2><<<GEMM_GRID, 256, 0, stream>>>(buf, W2, b2, snorm, buf, stats);

    // ---- batch norm fold + residual ----
    bn_prep_kernel<<<1, D, 0, stream>>>(stats, gamma, beta, sc_sh);
    finalize_kernel<<<NN * D / 4 / 256, 256, 0, stream>>>(buf, h, sc_sh, out);
}

// Round 5
// 532.358 us; speedup vs baseline: 1.0855x; 1.0855x over previous
//
#include <hip/hip_runtime.h>

#define D 128
#define NN 100000
#define NE 1600000
#define SCAN_NBLK 98        // ceil(NN / 1024)
#define GT_ROWS 128
#define GEMM_NT ((NN + GT_ROWS - 1) / GT_ROWS)   // 782
#define GEMM_GRID 512
#define NRANGE 8
#define RANGE_SZ 12500
#define STREAM_CAP 204800   // 200000 avg + 11 sigma slack
#define BINA_GRID 256
#define FILLB_GRID 1024

// ---------------------------------------------------------------------------
// K0: init the 8 stream cursors
// ---------------------------------------------------------------------------
__global__ void init8_kernel(unsigned int* __restrict__ gcur8)
{
    if (threadIdx.x < NRANGE) gcur8[threadIdx.x] = threadIdx.x * STREAM_CAP;
}

// ---------------------------------------------------------------------------
// K1: fused degree-count + XCD-range binning.
// pass1: cnt8x[blockIdx%8][dst]++ (XCD-local L2) and cnt8[dst/12500]++ (LDS)
// pass2: write packed (dstLocal<<17 | src) into per-range stream
// ---------------------------------------------------------------------------
__global__ __launch_bounds__(256) void bin_count_kernel(
    const int* __restrict__ src, const int* __restrict__ dst,
    int* __restrict__ cnt8x, unsigned int* __restrict__ gcur8,
    unsigned int* __restrict__ stream)
{
    __shared__ unsigned int cnt8[NRANGE], base8[NRANGE], off8[NRANGE];
    const int tid = threadIdx.x;
    if (tid < NRANGE) cnt8[tid] = 0;
    __syncthreads();
    int* mycnt = cnt8x + (size_t)(blockIdx.x & 7) * NN;
    const int NT4 = NE / 4;
    // pass 1
    for (int i4 = blockIdx.x * 256 + tid; i4 < NT4; i4 += BINA_GRID * 256) {
        int4 d = ((const int4*)dst)[i4];
        atomicAdd(&mycnt[d.x], 1);
        atomicAdd(&mycnt[d.y], 1);
        atomicAdd(&mycnt[d.z], 1);
        atomicAdd(&mycnt[d.w], 1);
        atomicAdd(&cnt8[d.x / RANGE_SZ], 1u);
        atomicAdd(&cnt8[d.y / RANGE_SZ], 1u);
        atomicAdd(&cnt8[d.z / RANGE_SZ], 1u);
        atomicAdd(&cnt8[d.w / RANGE_SZ], 1u);
    }
    __syncthreads();
    if (tid < NRANGE) {
        base8[tid] = atomicAdd(&gcur8[tid], cnt8[tid]);
        off8[tid]  = 0;
    }
    __syncthreads();
    // pass 2
    for (int i4 = blockIdx.x * 256 + tid; i4 < NT4; i4 += BINA_GRID * 256) {
        int4 d = ((const int4*)dst)[i4];
        int4 s = ((const int4*)src)[i4];
        {
            int r = d.x / RANGE_SZ; unsigned dl = (unsigned)(d.x - r * RANGE_SZ);
            unsigned pos = base8[r] + atomicAdd(&off8[r], 1u);
            stream[pos] = (dl << 17) | (unsigned)s.x;
        }
        {
            int r = d.y / RANGE_SZ; unsigned dl = (unsigned)(d.y - r * RANGE_SZ);
            unsigned pos = base8[r] + atomicAdd(&off8[r], 1u);
            stream[pos] = (dl << 17) | (unsigned)s.y;
        }
        {
            int r = d.z / RANGE_SZ; unsigned dl = (unsigned)(d.z - r * RANGE_SZ);
            unsigned pos = base8[r] + atomicAdd(&off8[r], 1u);
            stream[pos] = (dl << 17) | (unsigned)s.z;
        }
        {
            int r = d.w / RANGE_SZ; unsigned dl = (unsigned)(d.w - r * RANGE_SZ);
            unsigned pos = base8[r] + atomicAdd(&off8[r], 1u);
            stream[pos] = (dl << 17) | (unsigned)s.w;
        }
    }
}

// ---------------------------------------------------------------------------
// K2: per-block exclusive scan (1024 elements / block), summing 8 XCD copies
// ---------------------------------------------------------------------------
__global__ __launch_bounds__(256) void scan_local_kernel(
    const int* __restrict__ cnt8x, int* __restrict__ pre, int* __restrict__ blkSum)
{
    __shared__ int lds[256];
    const int t = threadIdx.x;
    const int base = blockIdx.x * 1024 + t * 4;
    int4 v = {0, 0, 0, 0};
    if (base + 3 < NN) {
#pragma unroll
        for (int r = 0; r < NRANGE; ++r) {
            int4 c = *(const int4*)&cnt8x[(size_t)r * NN + base];
            v.x += c.x; v.y += c.y; v.z += c.z; v.w += c.w;
        }
    } else {
#pragma unroll
        for (int r = 0; r < NRANGE; ++r) {
            if (base + 0 < NN) v.x += cnt8x[(size_t)r * NN + base + 0];
            if (base + 1 < NN) v.y += cnt8x[(size_t)r * NN + base + 1];
            if (base + 2 < NN) v.z += cnt8x[(size_t)r * NN + base + 2];
            if (base + 3 < NN) v.w += cnt8x[(size_t)r * NN + base + 3];
        }
    }
    const int s = v.x + v.y + v.z + v.w;
    lds[t] = s;
    __syncthreads();
    for (int off = 1; off < 256; off <<= 1) {
        int val = 0;
        if (t >= off) val = lds[t - off];
        __syncthreads();
        if (t >= off) lds[t] += val;
        __syncthreads();
    }
    const int excl = lds[t] - s;
    if (t == 255) blkSum[blockIdx.x] = lds[255];
    int4 o;
    o.x = excl;
    o.y = excl + v.x;
    o.z = excl + v.x + v.y;
    o.w = excl + v.x + v.y + v.z;
    if (base + 3 < NN) *(int4*)&pre[base] = o;
    else {
        if (base + 0 < NN) pre[base + 0] = o.x;
        if (base + 1 < NN) pre[base + 1] = o.y;
        if (base + 2 < NN) pre[base + 2] = o.z;
        if (base + 3 < NN) pre[base + 3] = o.w;
    }
}

// ---------------------------------------------------------------------------
// K3: scan the 98 block sums (single block)
// ---------------------------------------------------------------------------
__global__ __launch_bounds__(128) void scan_blk_kernel(
    const int* __restrict__ blkSum, int* __restrict__ blkOfs)
{
    __shared__ int lds[128];
    const int t = threadIdx.x;
    int s = (t < SCAN_NBLK) ? blkSum[t] : 0;
    lds[t] = s;
    __syncthreads();
    for (int off = 1; off < 128; off <<= 1) {
        int val = 0;
        if (t >= off) val = lds[t - off];
        __syncthreads();
        if (t >= off) lds[t] += val;
        __syncthreads();
    }
    blkOfs[t] = lds[t] - s;
}

// ---------------------------------------------------------------------------
// K4: row_start[n] = pre[n] + blkOfs[n/1024]; cursor = copy
// ---------------------------------------------------------------------------
__global__ __launch_bounds__(256) void scan_finish_kernel(
    const int* __restrict__ pre, const int* __restrict__ blkOfs,
    int* __restrict__ row_start, int* __restrict__ cursor)
{
    int n = blockIdx.x * 256 + threadIdx.x;
    if (n > NN) return;
    int v = (n == NN) ? NE : pre[n] + blkOfs[n >> 10];
    row_start[n] = v;
    if (n < NN) cursor[n] = v;
}

// ---------------------------------------------------------------------------
// K5: fill eidx from the 8 streams; block b handles stream b&7 so each
// dst-range's cursor/eidx lines are owned by one XCD
// ---------------------------------------------------------------------------
__global__ __launch_bounds__(256) void fill_kernel(
    const unsigned int* __restrict__ stream, const unsigned int* __restrict__ gcur8,
    int* __restrict__ cursor, int* __restrict__ eidx)
{
    const int r = blockIdx.x & 7;
    const int chunk = blockIdx.x >> 3;               // 0..127
    const unsigned s1 = gcur8[r];                    // stream end
    const unsigned stride = (FILLB_GRID / 8) * 256;  // 32768
    for (unsigned i = (unsigned)r * STREAM_CAP + chunk * 256 + threadIdx.x;
         i < s1; i += stride) {
        unsigned p = stream[i];
        int s  = (int)(p & 0x1FFFFu);
        int dn = r * RANGE_SZ + (int)(p >> 17);
        int pos = atomicAdd(&cursor[dn], 1);
        eidx[pos] = s;
    }
}

// ---------------------------------------------------------------------------
// K6: gather  x[n] = (1+eps)*h[n] + sum_{e in csr(n)} h[eidx[e]]
// ---------------------------------------------------------------------------
__global__ __launch_bounds__(256) void gather_kernel(
    const float* __restrict__ h, const int* __restrict__ row_start,
    const int* __restrict__ eidx, const float* __restrict__ epsp,
    float* __restrict__ x)
{
    int gid  = blockIdx.x * 256 + threadIdx.x;
    int node = gid >> 5;
    int lane = gid & 31;
    if (node >= NN) return;
    const int s0 = row_start[node];
    const int s1 = row_start[node + 1];
    const float sc = 1.0f + epsp[0];
    float4 hv = ((const float4*)(h + (size_t)node * D))[lane];
    float ax = sc * hv.x, ay = sc * hv.y, az = sc * hv.z, aw = sc * hv.w;
    float bx = 0.f, by = 0.f, bz = 0.f, bw = 0.f;
    int e = s0;
    for (; e + 1 < s1; e += 2) {
        int sa = eidx[e];
        int sb = eidx[e + 1];
        float4 va = ((const float4*)(h + (size_t)sa * D))[lane];
        float4 vb = ((const float4*)(h + (size_t)sb * D))[lane];
        ax += va.x; ay += va.y; az += va.z; aw += va.w;
        bx += vb.x; by += vb.y; bz += vb.z; bw += vb.w;
    }
    if (e < s1) {
        int sa = eidx[e];
        float4 va = ((const float4*)(h + (size_t)sa * D))[lane];
        ax += va.x; ay += va.y; az += va.z; aw += va.w;
    }
    float4 o = {ax + bx, ay + by, az + bz, aw + bw};
    ((float4*)(x + (size_t)node * D))[lane] = o;
}

// ---------------------------------------------------------------------------
// K7/K8: GEMM, half-K LDS tiling. Per block: W-half [64][128] (32KB) +
// x-half [64][128] transposed+XOR-swizzled (32KB) = 64KB -> 2 blocks/CU,
// 8 waves/CU. 8x8 micro-tile, register-staged prefetch of next half.
// MODE 1: out = relu(x@W + b)
// MODE 2: out = (x@W + b) * snorm, fused per-column sum/sumsq -> stats
// ---------------------------------------------------------------------------
template <int MODE>
__global__ __launch_bounds__(256, 2) void gemm_kernel(
    const float* __restrict__ xin, const float* __restrict__ W,
    const float* __restrict__ bias, const float* __restrict__ snorm,
    float* __restrict__ out, double* __restrict__ stats)
{
    __shared__ float wl[64 * D];   // 32 KB  [kloc][col]
    __shared__ float xb[64 * D];   // 32 KB  [kloc][row ^ swz]
    const int tid = threadIdx.x;
    const int cg = tid & 15;             // col group
    const int rg = tid >> 4;             // row group (0..15)
    const int ca = cg * 4;               // cols ca..ca+3
    const int cb = 64 + cg * 4;          // cols cb..cb+3

    float4 bva = ((const float4*)bias)[cg];
    float4 bvb = ((const float4*)bias)[16 + cg];

    float ssum[8], ssq[8];
#pragma unroll
    for (int j = 0; j < 8; ++j) { ssum[j] = 0.f; ssq[j] = 0.f; }

    float4 xs[8], wsg[8];
    // x: idx=tid+i*256: row=idx>>4 (0..127), kc=idx&15 (k-float4 within half)
    // w: idx=tid+i*256: k=idx>>5 (0..63), c4=idx&31
    auto LOADG = [&](int t, int hh) {
        const int row0 = t * GT_ROWS;
#pragma unroll
        for (int i = 0; i < 8; ++i) {
            int idx = tid + i * 256;
            int row = idx >> 4;
            int kc  = idx & 15;
            int grow = row0 + row;
            xs[i] = (grow < NN)
                ? ((const float4*)(xin + (size_t)grow * D))[hh * 16 + kc]
                : make_float4(0.f, 0.f, 0.f, 0.f);
        }
#pragma unroll
        for (int i = 0; i < 8; ++i) {
            int idx = tid + i * 256;
            int k  = idx >> 5;
            int c4 = idx & 31;
            wsg[i] = ((const float4*)(W + (size_t)(hh * 64 + k) * D))[c4];
        }
    };
    auto WRITEL = [&]() {
#pragma unroll
        for (int i = 0; i < 8; ++i) {
            int idx = tid + i * 256;
            int row = idx >> 4;
            int kc  = idx & 15;
            float v[4] = {xs[i].x, xs[i].y, xs[i].z, xs[i].w};
#pragma unroll
            for (int j = 0; j < 4; ++j)
                xb[(kc * 4 + j) * D + (row ^ (kc << 2))] = v[j];
        }
#pragma unroll
        for (int i = 0; i < 8; ++i) {
            int idx = tid + i * 256;
            int k  = idx >> 5;
            int c4 = idx & 31;
            *(float4*)&wl[k * D + c4 * 4] = wsg[i];
        }
    };

    bool first = true;
    for (int t = blockIdx.x; t < GEMM_NT; t += GEMM_GRID) {
        float acc[8][8];
#pragma unroll
        for (int i = 0; i < 8; ++i)
#pragma unroll
            for (int j = 0; j < 8; ++j) acc[i][j] = 0.f;

#pragma unroll 1
        for (int hh = 0; hh < 2; ++hh) {
            if (first) { LOADG(t, 0); first = false; }
            __syncthreads();             // LDS free (prev compute done)
            WRITEL();
            int nt = (hh == 0) ? t : t + GEMM_GRID;
            int nh = hh ^ 1;
            if (nt < GEMM_NT) LOADG(nt, nh);   // prefetch next half
            __syncthreads();             // LDS ready

#pragma unroll 8
            for (int k = 0; k < 64; ++k) {
                const int V = ((k >> 2) & 15) << 2;
                float4 xa = *(const float4*)&xb[k * D + ((rg * 8) ^ V)];
                float4 xc = *(const float4*)&xb[k * D + ((rg * 8 + 4) ^ V)];
                float4 wa = *(const float4*)&wl[k * D + ca];
                float4 wb = *(const float4*)&wl[k * D + cb];
                float xr[8] = {xa.x, xa.y, xa.z, xa.w, xc.x, xc.y, xc.z, xc.w};
                float wr[8] = {wa.x, wa.y, wa.z, wa.w, wb.x, wb.y, wb.z, wb.w};
#pragma unroll
                for (int i = 0; i < 8; ++i)
#pragma unroll
                    for (int j = 0; j < 8; ++j)
                        acc[i][j] = fmaf(xr[i], wr[j], acc[i][j]);
            }
        }

        // ---- epilogue ----
#pragma unroll
        for (int i = 0; i < 8; ++i) {
            int row = t * GT_ROWS + rg * 8 + i;
            if (row < NN) {
                float oa[4], ob[4];
                if (MODE == 1) {
                    oa[0] = fmaxf(acc[i][0] + bva.x, 0.f);
                    oa[1] = fmaxf(acc[i][1] + bva.y, 0.f);
                    oa[2] = fmaxf(acc[i][2] + bva.z, 0.f);
                    oa[3] = fmaxf(acc[i][3] + bva.w, 0.f);
                    ob[0] = fmaxf(acc[i][4] + bvb.x, 0.f);
                    ob[1] = fmaxf(acc[i][5] + bvb.y, 0.f);
                    ob[2] = fmaxf(acc[i][6] + bvb.z, 0.f);
                    ob[3] = fmaxf(acc[i][7] + bvb.w, 0.f);
                } else {
                    const float sn = snorm[row];
                    oa[0] = (acc[i][0] + bva.x) * sn;
                    oa[1] = (acc[i][1] + bva.y) * sn;
                    oa[2] = (acc[i][2] + bva.z) * sn;
                    oa[3] = (acc[i][3] + bva.w) * sn;
                    ob[0] = (acc[i][4] + bvb.x) * sn;
                    ob[1] = (acc[i][5] + bvb.y) * sn;
                    ob[2] = (acc[i][6] + bvb.z) * sn;
                    ob[3] = (acc[i][7] + bvb.w) * sn;
#pragma unroll
                    for (int j = 0; j < 4; ++j) {
                        ssum[j]     += oa[j];  ssq[j]     += oa[j] * oa[j];
                        ssum[4 + j] += ob[j];  ssq[4 + j] += ob[j] * ob[j];
                    }
                }
                float* op = out + (size_t)row * D;
                *(float4*)&op[ca] = *(float4*)&oa[0];
                *(float4*)&op[cb] = *(float4*)&ob[0];
            }
        }
    }

    // ---- fused BN stats reduce (MODE 2): reuse xb as scratch ----
    if (MODE == 2) {
        float* red = xb;   // needs 16*128 floats, xb has 8192
        __syncthreads();
#pragma unroll
        for (int j = 0; j < 4; ++j) {
            red[rg * D + ca + j] = ssum[j];
            red[rg * D + cb + j] = ssum[4 + j];
        }
        __syncthreads();
        if (tid < D) {
            float s = 0.f;
#pragma unroll
            for (int r = 0; r < 16; ++r) s += red[r * D + tid];
            atomicAdd(&stats[tid], (double)s);
        }
        __syncthreads();
#pragma unroll
        for (int j = 0; j < 4; ++j) {
            red[rg * D + ca + j] = ssq[j];
            red[rg * D + cb + j] = ssq[4 + j];
        }
        __syncthreads();
        if (tid < D) {
            float s = 0.f;
#pragma unroll
            for (int r = 0; r < 16; ++r) s += red[r * D + tid];
            atomicAdd(&stats[D + tid], (double)s);
        }
    }
}

// ---------------------------------------------------------------------------
// K9: fold stats into per-column scale/shift
// ---------------------------------------------------------------------------
__global__ void bn_prep_kernel(const double* __restrict__ stats,
                               const float* __restrict__ gamma,
                               const float* __restrict__ beta,
                               float* __restrict__ sc_sh)
{
    int c = threadIdx.x;
    double mean = stats[c] * (1.0 / NN);
    double var  = stats[D + c] * (1.0 / NN) - mean * mean;
    float rs = rsqrtf((float)var + 1e-5f);
    float sc = gamma[c] * rs;
    sc_sh[c]     = sc;
    sc_sh[D + c] = beta[c] - (float)mean * sc;
}

// ---------------------------------------------------------------------------
// K10: out = h + relu(y*sc + sh)
// ---------------------------------------------------------------------------
__global__ __launch_bounds__(256) void finalize_kernel(
    const float* __restrict__ y, const float* __restrict__ h,
    const float* __restrict__ sc_sh, float* __restrict__ out)
{
    int i  = blockIdx.x * 256 + threadIdx.x;
    int cf = i & 31;
    float4 yv = ((const float4*)y)[i];
    float4 hv = ((const float4*)h)[i];
    float4 sc = ((const float4*)sc_sh)[cf];
    float4 sh = ((const float4*)(sc_sh + D))[cf];
    float4 o;
    o.x = hv.x + fmaxf(fmaf(yv.x, sc.x, sh.x), 0.0f);
    o.y = hv.y + fmaxf(fmaf(yv.y, sc.y, sh.y), 0.0f);
    o.z = hv.z + fmaxf(fmaf(yv.z, sc.z, sh.z), 0.0f);
    o.w = hv.w + fmaxf(fmaf(yv.w, sc.w, sh.w), 0.0f);
    ((float4*)out)[i] = o;
}

// ---------------------------------------------------------------------------
extern "C" void kernel_launch(void* const* d_in, const int* in_sizes, int n_in,
                              void* d_out, int out_size, void* d_ws, size_t ws_size,
                              hipStream_t stream)
{
    const float* h     = (const float*)d_in[0];
    const float* snorm = (const float*)d_in[1];
    const float* eps   = (const float*)d_in[2];
    const float* W1    = (const float*)d_in[3];
    const float* b1    = (const float*)d_in[4];
    const float* W2    = (const float*)d_in[5];
    const float* b2    = (const float*)d_in[6];
    const float* gamma = (const float*)d_in[7];
    const float* beta  = (const float*)d_in[8];
    const int*   src   = (const int*)d_in[9];
    const int*   dst   = (const int*)d_in[10];
    float* out = (float*)d_out;

    char* ws = (char*)d_ws;
    const size_t BUF_BYTES = (size_t)NN * D * sizeof(float);   // 51.2 MB
    float*  buf       = (float*)ws;                            // x -> hidden -> y
    double* stats     = (double*)(ws + BUF_BYTES);             // 256 doubles
    float*  sc_sh     = (float*)(ws + BUF_BYTES + 2048);       // 256 floats
    char*   p         = ws + BUF_BYTES + 4096;
    int*    pre       = (int*)p;            p += (size_t)NN * 4;
    int*    row_start = (int*)p;            p += (size_t)(NN + 4) * 4;
    int*    cursor    = (int*)p;            p += (size_t)NN * 4;
    int*    blkSum    = (int*)p;            p += 512;
    int*    blkOfs    = (int*)p;            p += 512;
    unsigned int* gcur8  = (unsigned int*)p;  p += 256;
    int*    eidx      = (int*)p;            p += (size_t)NE * 4;          // 6.4 MB
    unsigned int* stream8 = (unsigned int*)p;                             // 6.55 MB
    // cnt8x (8 XCD-local degree-count copies, 3.2 MB) aliases eidx: it is
    // consumed by scan_local before fill_kernel overwrites eidx.
    int*    cnt8x     = eidx;

    hipMemsetAsync(cnt8x, 0, (size_t)NRANGE * NN * 4, stream);
    hipMemsetAsync(stats, 0, 2048, stream);
    init8_kernel<<<1, 64, 0, stream>>>(gcur8);

    // ---- CSR build: fused count+bin, scan, XCD-local fill ----
    bin_count_kernel<<<BINA_GRID, 256, 0, stream>>>(src, dst, cnt8x, gcur8, stream8);
    scan_local_kernel<<<SCAN_NBLK, 256, 0, stream>>>(cnt8x, pre, blkSum);
    scan_blk_kernel<<<1, 128, 0, stream>>>(blkSum, blkOfs);
    scan_finish_kernel<<<(NN + 256) / 256 + 1, 256, 0, stream>>>(pre, blkOfs, row_start, cursor);
    fill_kernel<<<FILLB_GRID, 256, 0, stream>>>(stream8, gcur8, cursor, eidx);

    // ---- gather: x = (1+eps)*h + segment_sum(h[src] by dst) ----
    gather_kernel<<<NN * 32 / 256, 256, 0, stream>>>(h, row_start, eidx, eps, buf);

    // ---- MLP (in-place on buf), BN stats fused into GEMM2 ----
    gemm_kernel<1><<<GEMM_GRID, 256, 0, stream>>>(buf, W1, b1, nullptr, buf, nullptr);
    gemm_kernel<2><<<GEMM_GRID, 256, 0, stream>>>(buf, W2, b2, snorm, buf, stats);

    // ---- batch norm fold + residual ----
    bn_prep_kernel<<<1, D, 0, stream>>>(stats, gamma, beta, sc_sh);
    finalize_kernel<<<NN * D / 4 / 256, 256, 0, stream>>>(buf, h, sc_sh, out);
}